// Round 5
// baseline (370.022 us; speedup 1.0000x reference)
//
#include <hip/hip_runtime.h>

// LocalFeatureAggregation — bf16-MFMA pipeline, point-major activations.
// B=2, N=16384, K=16, D_IN=128, D_OUT=256, GROUPS=16.
//
// Round-5 changes:
//  - pool1/pool2 GEMMs fused into lse_pool_kernel: the 16-pt tile's m row
//    (geo-GN-relu-meanK ++ gather-meanK) goes to an 8.4 KB LDS Mbuf, then the
//    256->POOL_COUT conv runs in-block (A-fragments streamed from L2).
//    Kills the M global round-trip and both pool dispatches.
//  - geo-weight Abuf dropped: A-fragments b128-loaded directly from global.

constexpr int Bc = 2;
constexpr int Nc = 16384;
constexpr int Kc = 16;
constexpr float EPSc = 1e-6f;

typedef __attribute__((ext_vector_type(8))) short short8;
typedef __attribute__((ext_vector_type(4))) short short4v;
typedef __attribute__((ext_vector_type(4))) float floatx4;

__device__ inline short f2bf(float x) {
    union { float f; unsigned u; } v; v.f = x;
    unsigned r = v.u + 0x7fffu + ((v.u >> 16) & 1u);
    return (short)(r >> 16);
}
__device__ inline float bf2f(short s) {
    union { unsigned u; float f; } v;
    v.u = ((unsigned)(unsigned short)s) << 16;
    return v.f;
}

// ---- workspace layout ----
// f32 ST[1024]: ST_SC=0, ST_P1=64, ST_P2=128, ST_GEO=256 (B x 65)
// then bf16 (short) region, offsets in shorts:
constexpr size_t OW_W1  = 0;                        // 128*128
constexpr size_t OW_P1W = OW_W1  + 128*128;         // 128*256
constexpr size_t OW_P2W = OW_P1W + 128*256;         // 256*256
constexpr size_t OW_M2W = OW_P2W + 256*256;         // 512*256
constexpr size_t OW_SCW = OW_M2W + 512*256;         // 512*128
constexpr size_t OW_L1W = OW_SCW + 512*128;         // 128*32 (K padded)
constexpr size_t OW_L2W = OW_L1W + 128*32;          // 128*32
constexpr size_t OW_FB  = OW_L2W + 128*32;          // B*N*128
constexpr size_t OW_X1  = OW_FB  + (size_t)Bc*Nc*128;
constexpr size_t OW_Z1  = OW_X1  + (size_t)Bc*Nc*128;
constexpr size_t OW_Z2  = OW_Z1  + (size_t)Bc*Nc*128;
constexpr size_t OW_S   = OW_Z2  + (size_t)Bc*Nc*256;

// prep_kernel segment bounds (elements)
constexpr int CV0 = 128*128;            // w1
constexpr int CV1 = CV0 + 128*256;      // pool1_w
constexpr int CV2 = CV1 + 256*256;      // pool2_w
constexpr int CV3 = CV2 + 512*256;      // mlp2_w
constexpr int CV4 = CV3 + 512*128;      // sc_w
constexpr int CV5 = CV4 + 128*32;       // lse1_w padded
constexpr int CV6 = CV5 + 128*32;       // lse2_w padded
constexpr int CVTOT = CV6 + 1024;       // + zero ST

__global__ void prep_kernel(const float* __restrict__ w1,
                            const float* __restrict__ p1w,
                            const float* __restrict__ p2w,
                            const float* __restrict__ m2w,
                            const float* __restrict__ scw,
                            const float* __restrict__ l1w,
                            const float* __restrict__ l2w,
                            short* __restrict__ W16,
                            float* __restrict__ ST)
{
    int i = blockIdx.x * 256 + threadIdx.x;
    if (i < CV0) { W16[OW_W1  + i] = f2bf(w1[i]); return; }
    if (i < CV1) { int k = i - CV0; W16[OW_P1W + k] = f2bf(p1w[k]); return; }
    if (i < CV2) { int k = i - CV1; W16[OW_P2W + k] = f2bf(p2w[k]); return; }
    if (i < CV3) { int k = i - CV2; W16[OW_M2W + k] = f2bf(m2w[k]); return; }
    if (i < CV4) { int k = i - CV3; W16[OW_SCW + k] = f2bf(scw[k]); return; }
    if (i < CV5) { int k = i - CV4; int o = k >> 5, c = k & 31;
                   W16[OW_L1W + k] = (c < 10) ? f2bf(l1w[o*10+c]) : (short)0; return; }
    if (i < CV6) { int k = i - CV5; int o = k >> 5, c = k & 31;
                   W16[OW_L2W + k] = (c < 10) ? f2bf(l2w[o*10+c]) : (short)0; return; }
    { int k = i - CV6; if (k < 1024) ST[k] = 0.f; }
}

// features f32 [b][128][N] -> FB bf16 [b][N][128]
__global__ void feat_t_kernel(const float* __restrict__ in, short* __restrict__ out) {
    int tid  = threadIdx.x;
    int lane = tid & 63, wave = tid >> 6;
    int bb = blockIdx.x / (Nc / 64);
    int n  = (blockIdx.x % (Nc / 64)) * 64 + lane;
    #pragma unroll
    for (int cc = 0; cc < 4; cc++) {
        int c0 = (wave + cc * 4) * 8;
        short8 sv;
        #pragma unroll
        for (int i = 0; i < 8; i++)
            sv[i] = f2bf(in[((size_t)bb * 128 + c0 + i) * Nc + n]);
        *(short8*)&out[((size_t)(bb * Nc + n)) * 128 + c0] = sv;
    }
}

// Reduce S (10) and Q upper-tri (55) of geo over all (n,k), per batch.
// Grid-stride: 4 items accumulated in registers, then one butterfly/thread.
__launch_bounds__(256)
__global__ void geo_reduce_kernel(const float* __restrict__ coords,
                                  const int* __restrict__ knn_idx,
                                  const float* __restrict__ knn_dist,
                                  float* __restrict__ dst)   // [B][65]
{
    __shared__ float part[4][65];
    const int tid  = threadIdx.x;
    const int b    = blockIdx.y;
    const int base = blockIdx.x * 256 + tid;          // gridDim.x = 256
    const float* cb  = coords   + (size_t)b * Nc * 3;
    const int*   ib  = knn_idx  + (size_t)b * Nc * Kc;
    const float* db  = knn_dist + (size_t)b * Nc * Kc;

    float acc[65];
    #pragma unroll
    for (int i = 0; i < 65; i++) acc[i] = 0.f;

    #pragma unroll
    for (int it = 0; it < 4; it++) {
        int r = base + it * 65536;                    // covers Nc*Kc = 262144
        int n = r >> 4;
        float cx = cb[n*3+0], cy = cb[n*3+1], cz = cb[n*3+2];
        int   j  = ib[r];
        float nx = cb[j*3+0], ny = cb[j*3+1], nz = cb[j*3+2];
        float d  = db[r];
        float g[10] = {cx,cy,cz,nx,ny,nz,cx-nx,cy-ny,cz-nz,d};
        #pragma unroll
        for (int c = 0; c < 10; c++) acc[c] += g[c];
        int idx = 10;
        #pragma unroll
        for (int c = 0; c < 10; c++)
            #pragma unroll
            for (int c2 = c; c2 < 10; c2++) acc[idx++] += g[c] * g[c2];
    }
    #pragma unroll
    for (int i = 0; i < 65; i++) {
        float v = acc[i];
        #pragma unroll
        for (int off = 1; off < 64; off <<= 1) v += __shfl_xor(v, off);
        acc[i] = v;
    }
    int lane = tid & 63, wave = tid >> 6;
    if (lane == 0) {
        #pragma unroll
        for (int i = 0; i < 65; i++) part[wave][i] = acc[i];
    }
    __syncthreads();
    if (tid < 65) {
        float s = part[0][tid] + part[1][tid] + part[2][tid] + part[3][tid];
        atomicAdd(&dst[b * 65 + tid], s);
    }
}

// GEMM: out[b][n][o] = sum_c W[o][c] * X[b][n][c] + bias[o]   (point-major)
// MODE 1: leaky 0.2 -> bf16.  MODE 2: raw bf16 + group stats atomics.
// MODE 3: final — B input normalized during staging (pool2 GN+relu, 16ch
//         groups), epilogue v + GN(sbuf) -> leaky 0.01 -> f32 [b][o][n].
template<int CIN, int COUT, int GROUP_CH, int MODE>
__launch_bounds__(256)
__global__ void gemm_conv(const short* __restrict__ wA,   // [COUT][CIN] bf16
                          const short* __restrict__ xB,   // [b][N][CIN] bf16
                          const float* __restrict__ bias,
                          short* __restrict__ outb,
                          float* __restrict__ outf,
                          float* __restrict__ stats,
                          const short* __restrict__ sbuf, // [b][N][512] bf16
                          const float* __restrict__ st_sc,
                          const float* __restrict__ gw,
                          const float* __restrict__ gb,
                          float sc_cnt,
                          const float* __restrict__ bst,  // MODE 3: pool2 stats
                          const float* __restrict__ bgw,
                          const float* __restrict__ bgb,
                          float bcnt)
{
    __shared__ short Abuf[128 * 40];
    __shared__ short Bbuf[128 * 40];
    __shared__ float sstat[32];
    __shared__ float smean[4], sinv[4];
    __shared__ float bsc[256], bsh[256];

    const int tid  = threadIdx.x;
    const int n0   = blockIdx.x * 128;
    const int mo   = blockIdx.y * 128;
    const int b    = blockIdx.z;
    const int lane = tid & 63;
    const int wave = tid >> 6;
    const int wm   = (wave >> 1) * 64;
    const int wn   = (wave & 1) * 64;
    const int l15  = lane & 15;
    const int quad = lane >> 4;

    if constexpr (MODE == 2) { if (tid < 32) sstat[tid] = 0.f; }
    if constexpr (MODE == 3) {
        if (tid < 4) {
            int g = (mo >> 5) + tid;
            float s0 = st_sc[(b * 16 + g) * 2 + 0];
            float s1 = st_sc[(b * 16 + g) * 2 + 1];
            float mean = s0 / sc_cnt;
            float var  = s1 / sc_cnt - mean * mean;
            smean[tid] = mean;
            sinv[tid]  = rsqrtf(var + EPSc);
        }
        if (tid < CIN) {   // pool2 GN: 256 ch, 16 ch/group
            int g = tid >> 4;
            float s0 = bst[(b * 16 + g) * 2 + 0];
            float s1 = bst[(b * 16 + g) * 2 + 1];
            float mean = s0 / bcnt;
            float var  = s1 / bcnt - mean * mean;
            float inv  = rsqrtf(var + EPSc);
            float sc_  = inv * bgw[tid];
            bsc[tid] = sc_;
            bsh[tid] = bgb[tid] - mean * sc_;
        }
    }

    floatx4 acc[4][4];
    #pragma unroll
    for (int mi = 0; mi < 4; mi++)
        #pragma unroll
        for (int ni = 0; ni < 4; ni++)
            acc[mi][ni] = (floatx4){0.f, 0.f, 0.f, 0.f};

    const short* wAr = wA + (size_t)mo * CIN;
    const short* xBr = xB + (size_t)b * Nc * CIN + (size_t)n0 * CIN;

    for (int c0 = 0; c0 < CIN; c0 += 32) {
        __syncthreads();
        #pragma unroll
        for (int s = 0; s < 2; s++) {
            int e = tid + s * 256;
            int r = e >> 2, q = e & 3;
            *(short8*)&Abuf[r * 40 + q * 8] =
                *(const short8*)(wAr + (size_t)r * CIN + c0 + q * 8);
            short8 v = *(const short8*)(xBr + (size_t)r * CIN + c0 + q * 8);
            if constexpr (MODE == 3) {
                #pragma unroll
                for (int i = 0; i < 8; i++) {
                    int ch = c0 + q * 8 + i;
                    float t = bf2f(v[i]) * bsc[ch] + bsh[ch];
                    v[i] = f2bf(t > 0.f ? t : 0.f);
                }
            }
            *(short8*)&Bbuf[r * 40 + q * 8] = v;
        }
        __syncthreads();

        short8 af[4], bfr[4];
        #pragma unroll
        for (int mi = 0; mi < 4; mi++)
            af[mi] = *(short8*)&Abuf[(wm + mi * 16 + l15) * 40 + quad * 8];
        #pragma unroll
        for (int ni = 0; ni < 4; ni++)
            bfr[ni] = *(short8*)&Bbuf[(wn + ni * 16 + l15) * 40 + quad * 8];
        #pragma unroll
        for (int mi = 0; mi < 4; mi++)
            #pragma unroll
            for (int ni = 0; ni < 4; ni++)
                acc[mi][ni] = __builtin_amdgcn_mfma_f32_16x16x32_bf16(
                    af[mi], bfr[ni], acc[mi][ni], 0, 0, 0);
    }

    // D row(o) = mo+wm+mi*16+quad*4+r, col(n) = n0+wn+ni*16+l15
    #pragma unroll
    for (int mi = 0; mi < 4; mi++) {
        int rowl = wm + mi * 16 + quad * 4;
        float b4[4], gw4[4], gb4[4];
        #pragma unroll
        for (int r = 0; r < 4; r++) {
            b4[r] = bias[mo + rowl + r];
            if constexpr (MODE == 3) {
                gw4[r] = gw[mo + rowl + r];
                gb4[r] = gb[mo + rowl + r];
            }
        }
        float gs = 0.f, gq = 0.f;
        #pragma unroll
        for (int ni = 0; ni < 4; ni++) {
            int col = n0 + wn + ni * 16 + l15;
            if constexpr (MODE == 3) {
                short4v s4 = *(const short4v*)&sbuf[((size_t)(b * Nc + col)) * 512 + mo + rowl];
                int gl = rowl >> 5;
                #pragma unroll
                for (int r = 0; r < 4; r++) {
                    float v = acc[mi][ni][r] + b4[r];
                    float s = bf2f(s4[r]);
                    float sn = (s - smean[gl]) * sinv[gl] * gw4[r] + gb4[r];
                    float o = v + sn;
                    o = o > 0.f ? o : 0.01f * o;
                    outf[((size_t)b * COUT + mo + rowl + r) * Nc + col] = o;
                }
            } else {
                short4v sv;
                #pragma unroll
                for (int r = 0; r < 4; r++) {
                    float v = acc[mi][ni][r] + b4[r];
                    if constexpr (MODE == 1) v = v > 0.f ? v : 0.2f * v;
                    if constexpr (MODE == 2) { gs += v; gq += v * v; }
                    sv[r] = f2bf(v);
                }
                *(short4v*)&outb[((size_t)(b * Nc + col)) * COUT + mo + rowl] = sv;
            }
        }
        if constexpr (MODE == 2) {
            #pragma unroll
            for (int off = 1; off < 16; off <<= 1) {
                gs += __shfl_xor(gs, off);
                gq += __shfl_xor(gq, off);
            }
            if (l15 == 0) {
                int gl = rowl / GROUP_CH;
                atomicAdd(&sstat[gl * 2 + 0], gs);
                atomicAdd(&sstat[gl * 2 + 1], gq);
            }
        }
    }
    if constexpr (MODE == 2) {
        __syncthreads();
        constexpr int NG = 128 / GROUP_CH;
        if (tid < 2 * NG) {
            int g0 = mo / GROUP_CH;
            atomicAdd(&stats[b * 32 + (g0 + (tid >> 1)) * 2 + (tid & 1)], sstat[tid]);
        }
    }
}

// LSE + pool fused: per 16-point tile.
//  - per-group GN stats for the geo conv from closed form (S/Q + f32 weights).
//  - geo conv via MFMA (A-frags from global), GN+relu+mean_k -> Mbuf[pt][0:128]
//  - neighbor gather-mean of point-major xprev -> Mbuf[pt][128:256]
//    (optional folded GN+relu on xprev: xst = pool1 stats, 8ch groups)
//  - pool conv 256 -> POOL_COUT from Mbuf (A-frags from global) -> raw bf16 Z
//    + per-group sum/sumsq atomics into pstats.
template<int POOL_COUT, int PGROUP>
__launch_bounds__(256)
__global__ void lse_pool_kernel(const float* __restrict__ coords,
                                const int* __restrict__ knn_idx,
                                const float* __restrict__ knn_dist,
                                const short* __restrict__ xprev,   // [b][N][128] bf16
                                const short* __restrict__ wpad,    // [128][32] bf16
                                const float* __restrict__ wf,      // [128][10] f32
                                const float* __restrict__ gbias,   // [128]
                                const float* __restrict__ ggw,
                                const float* __restrict__ ggb,
                                const float* __restrict__ geoS,    // [B][65]
                                const float* __restrict__ xst,     // pool1 stats or null
                                const float* __restrict__ xgw,
                                const float* __restrict__ xgb,
                                float xcnt,
                                const short* __restrict__ pw,      // [POOL_COUT][256] bf16
                                const float* __restrict__ pbias,
                                float* __restrict__ pstats,        // [B][16][2]
                                short* __restrict__ z)             // [b][N][POOL_COUT] bf16
{
    __shared__ short Bbuf[256 * 40];
    __shared__ short Mbuf[16 * 264];
    __shared__ int   jl[256];
    __shared__ float osum[128], osq[128];
    __shared__ float smean[16], sinv[16];
    __shared__ float xscs[128], xshs[128];
    __shared__ float sstat[32];

    const int tid = threadIdx.x;
    const int b   = blockIdx.x >> 10;          // Nc/16 = 1024
    const int n0  = (blockIdx.x & 1023) * 16;
    const float NK = (float)(Nc * Kc);
    const bool norm = (xst != nullptr);

    if (tid < 32) sstat[tid] = 0.f;
    // zero Bbuf (pad cols must be 0)
    {
        int* bz = (int*)Bbuf;
        #pragma unroll
        for (int i = 0; i < 20; i++) bz[tid + i * 256] = 0;
    }
    // closed-form per-channel sums + xprev GN scale/shift
    if (tid < 128) {
        const float* S = geoS + b * 65;
        float w[10];
        #pragma unroll
        for (int c = 0; c < 10; c++) w[c] = wf[tid * 10 + c];
        float wS = 0.f;
        #pragma unroll
        for (int c = 0; c < 10; c++) wS += w[c] * S[c];
        float q = 0.f;
        {
            int idx = 10;
            #pragma unroll
            for (int c = 0; c < 10; c++)
                #pragma unroll
                for (int c2 = c; c2 < 10; c2++) {
                    float t = w[c] * w[c2] * S[idx++];
                    q += (c == c2) ? t : 2.f * t;
                }
        }
        float bo = gbias[tid];
        osum[tid] = NK * bo + wS;
        osq[tid]  = NK * bo * bo + 2.f * bo * wS + q;
        if (norm) {   // pool1 GN: 128 ch, 8 ch/group
            int g = tid >> 3;
            float s0 = xst[(b * 16 + g) * 2 + 0];
            float s1 = xst[(b * 16 + g) * 2 + 1];
            float mean = s0 / xcnt;
            float var  = s1 / xcnt - mean * mean;
            float inv  = rsqrtf(var + EPSc);
            float sc_  = inv * xgw[tid];
            xscs[tid] = sc_;
            xshs[tid] = xgb[tid] - mean * sc_;
        }
    }
    __syncthreads();

    // geo features for the 16x16 (pt,k) tile -> Bbuf[col=k*16+pt][c]
    {
        int pt = tid & 15, k = tid >> 4;
        int n  = n0 + pt;
        const float* cb = coords + (size_t)b * Nc * 3;
        float cx = cb[n*3+0], cy = cb[n*3+1], cz = cb[n*3+2];
        int   j  = knn_idx[((size_t)b * Nc + n) * Kc + k];
        float nx = cb[j*3+0], ny = cb[j*3+1], nz = cb[j*3+2];
        float d  = knn_dist[((size_t)b * Nc + n) * Kc + k];
        float g[10] = {cx,cy,cz,nx,ny,nz,cx-nx,cy-ny,cz-nz,d};
        int col = k * 16 + pt;
        #pragma unroll
        for (int c = 0; c < 10; c++) Bbuf[col * 40 + c] = f2bf(g[c]);
        jl[col] = j;
    }
    __syncthreads();
    if (tid < 16) {
        float s = 0.f, q = 0.f;
        #pragma unroll
        for (int i = 0; i < 8; i++) { s += osum[tid * 8 + i]; q += osq[tid * 8 + i]; }
        float cnt  = 8.f * NK;
        float mean = s / cnt;
        float var  = q / cnt - mean * mean;
        smean[tid] = mean;
        sinv[tid]  = rsqrtf(var + EPSc);
    }
    __syncthreads();

    const int lane = tid & 63, wave = tid >> 6;
    const int l15 = lane & 15, quad = lane >> 4;
    // B fragments: tile ni <-> neighbor k, lane col <-> pt
    short8 bfr[16];
    #pragma unroll
    for (int ni = 0; ni < 16; ni++)
        bfr[ni] = *(short8*)&Bbuf[(ni * 16 + l15) * 40 + quad * 8];
    #pragma unroll
    for (int mt2 = 0; mt2 < 2; mt2++) {
        int mt = wave * 2 + mt2;
        short8 af = *(const short8*)(wpad + (mt * 16 + l15) * 32 + quad * 8);
        floatx4 acc[16];
        #pragma unroll
        for (int ni = 0; ni < 16; ni++) {
            acc[ni] = (floatx4){0.f, 0.f, 0.f, 0.f};
            acc[ni] = __builtin_amdgcn_mfma_f32_16x16x32_bf16(af, bfr[ni], acc[ni], 0, 0, 0);
        }
        short4v sv;
        #pragma unroll
        for (int r = 0; r < 4; r++) {
            int o = mt * 16 + quad * 4 + r;
            int g = o >> 3;
            float mu = smean[g], iv = sinv[g];
            float bo = gbias[o], gwo = ggw[o], gbo = ggb[o];
            float s = 0.f;
            #pragma unroll
            for (int ni = 0; ni < 16; ni++) {
                float v = (acc[ni][r] + bo - mu) * iv * gwo + gbo;
                s += v > 0.f ? v : 0.f;
            }
            sv[r] = f2bf(s * (1.f / 16.f));
        }
        *(short4v*)&Mbuf[l15 * 264 + mt * 16 + quad * 4] = sv;
    }

    // neighbor gather-mean: thread (cs, tp), 16 x b128 loads -> Mbuf[pt][128+]
    {
        int tp = tid & 15, cs = tid >> 4;
        float sc8[8], sh8[8];
        if (norm) {
            #pragma unroll
            for (int i = 0; i < 8; i++) { sc8[i] = xscs[cs*8+i]; sh8[i] = xshs[cs*8+i]; }
        }
        float acc8[8];
        #pragma unroll
        for (int i = 0; i < 8; i++) acc8[i] = 0.f;
        #pragma unroll
        for (int k = 0; k < 16; k++) {
            int j = jl[k * 16 + tp];
            short8 v = *(const short8*)&xprev[((size_t)(b * Nc + j)) * 128 + cs * 8];
            if (norm) {
                #pragma unroll
                for (int i = 0; i < 8; i++) {
                    float t = bf2f(v[i]) * sc8[i] + sh8[i];
                    acc8[i] += t > 0.f ? t : 0.f;
                }
            } else {
                #pragma unroll
                for (int i = 0; i < 8; i++) acc8[i] += bf2f(v[i]);
            }
        }
        short8 sv;
        #pragma unroll
        for (int i = 0; i < 8; i++) sv[i] = f2bf(acc8[i] * (1.f / 16.f));
        *(short8*)&Mbuf[tp * 264 + 128 + cs * 8] = sv;
    }
    __syncthreads();

    // pool conv: Z[pt][o] = sum_ch pw[o][ch] * Mbuf[pt][ch] + pbias[o]
    constexpr int MTW = POOL_COUT / 64;       // m-tiles per wave (2 or 4)
    floatx4 pacc[MTW];
    #pragma unroll
    for (int mi = 0; mi < MTW; mi++) pacc[mi] = (floatx4){0.f, 0.f, 0.f, 0.f};
    #pragma unroll
    for (int kc = 0; kc < 8; kc++) {
        short8 bfp = *(short8*)&Mbuf[l15 * 264 + kc * 32 + quad * 8];
        #pragma unroll
        for (int mi = 0; mi < MTW; mi++) {
            int mt = wave * MTW + mi;
            short8 afp = *(const short8*)(pw + (size_t)(mt * 16 + l15) * 256 + kc * 32 + quad * 8);
            pacc[mi] = __builtin_amdgcn_mfma_f32_16x16x32_bf16(afp, bfp, pacc[mi], 0, 0, 0);
        }
    }
    #pragma unroll
    for (int mi = 0; mi < MTW; mi++) {
        int mt = wave * MTW + mi;
        float gs = 0.f, gq = 0.f;
        short4v sv;
        #pragma unroll
        for (int r = 0; r < 4; r++) {
            int o = mt * 16 + quad * 4 + r;
            float v = pacc[mi][r] + pbias[o];
            gs += v; gq += v * v;
            sv[r] = f2bf(v);
        }
        *(short4v*)&z[((size_t)(b * Nc + n0 + l15)) * POOL_COUT + mt * 16 + quad * 4] = sv;
        #pragma unroll
        for (int off = 1; off < 16; off <<= 1) {
            gs += __shfl_xor(gs, off);
            gq += __shfl_xor(gq, off);
        }
        if (l15 == 0) {
            int g = (mt * 16 + quad * 4) / PGROUP;
            atomicAdd(&sstat[g * 2 + 0], gs);
            atomicAdd(&sstat[g * 2 + 1], gq);
        }
    }
    __syncthreads();
    if (tid < 32) atomicAdd(&pstats[b * 32 + tid], sstat[tid]);
}

extern "C" void kernel_launch(void* const* d_in, const int* in_sizes, int n_in,
                              void* d_out, int out_size, void* d_ws, size_t ws_size,
                              hipStream_t stream)
{
    const float* coords   = (const float*)d_in[0];
    const float* features = (const float*)d_in[1];
    const float* knn_dist = (const float*)d_in[2];
    const int*   knn_idx  = (const int*)  d_in[3];
    const float* w1       = (const float*)d_in[4];
    const float* b1       = (const float*)d_in[5];
    const float* lse1_w   = (const float*)d_in[6];
    const float* lse1_b   = (const float*)d_in[7];
    const float* lse1_gw  = (const float*)d_in[8];
    const float* lse1_gb  = (const float*)d_in[9];
    const float* pool1_w  = (const float*)d_in[10];
    const float* pool1_b  = (const float*)d_in[11];
    const float* pool1_gw = (const float*)d_in[12];
    const float* pool1_gb = (const float*)d_in[13];
    const float* lse2_w   = (const float*)d_in[14];
    const float* lse2_b   = (const float*)d_in[15];
    const float* lse2_gw  = (const float*)d_in[16];
    const float* lse2_gb  = (const float*)d_in[17];
    const float* pool2_w  = (const float*)d_in[18];
    const float* pool2_b  = (const float*)d_in[19];
    const float* pool2_gw = (const float*)d_in[20];
    const float* pool2_gb = (const float*)d_in[21];
    const float* mlp2_w   = (const float*)d_in[22];
    const float* mlp2_b   = (const float*)d_in[23];
    const float* sc_w     = (const float*)d_in[24];
    const float* sc_b     = (const float*)d_in[25];
    const float* sc_gw    = (const float*)d_in[26];
    const float* sc_gb    = (const float*)d_in[27];
    (void)in_sizes; (void)n_in; (void)out_size; (void)ws_size;

    float* ST = (float*)d_ws;           // 1024 floats
    float* ST_SC  = ST + 0;
    float* ST_P1  = ST + 64;
    float* ST_P2  = ST + 128;
    float* ST_GEO = ST + 256;           // B x 65
    short* W16 = (short*)(ST + 1024);
    short* W1b  = W16 + OW_W1;
    short* P1Wb = W16 + OW_P1W;
    short* P2Wb = W16 + OW_P2W;
    short* M2Wb = W16 + OW_M2W;
    short* SCWb = W16 + OW_SCW;
    short* L1Wb = W16 + OW_L1W;
    short* L2Wb = W16 + OW_L2W;
    short* FB   = W16 + OW_FB;
    short* X1B  = W16 + OW_X1;
    short* Z1   = W16 + OW_Z1;
    short* Z2   = W16 + OW_Z2;
    short* SB   = W16 + OW_S;
    float* out  = (float*)d_out;

    prep_kernel<<<(CVTOT + 255) / 256, 256, 0, stream>>>(
        w1, pool1_w, pool2_w, mlp2_w, sc_w, lse1_w, lse2_w, W16, ST);
    feat_t_kernel<<<Bc * Nc / 64, 256, 0, stream>>>(features, FB);
    geo_reduce_kernel<<<dim3(256, Bc), 256, 0, stream>>>(
        coords, knn_idx, knn_dist, ST_GEO);

    // sc: 128 -> 512, raw bf16 S + stats (group=32ch)
    gemm_conv<128,512,32,2><<<dim3(Nc/128, 4, Bc), 256, 0, stream>>>(
        SCWb, FB, sc_b, SB, nullptr, ST_SC, nullptr, nullptr, nullptr, nullptr, 0.f,
        nullptr, nullptr, nullptr, 0.f);
    // mlp1: 128 -> 128, leaky 0.2
    gemm_conv<128,128,8,1><<<dim3(Nc/128, 1, Bc), 256, 0, stream>>>(
        W1b, FB, b1, X1B, nullptr, nullptr, nullptr, nullptr, nullptr, nullptr, 0.f,
        nullptr, nullptr, nullptr, 0.f);
    // lse1 + pool1 (xprev = X1B, no folded GN) -> raw Z1 + ST_P1
    lse_pool_kernel<128,8><<<Bc * Nc / 16, 256, 0, stream>>>(
        coords, knn_idx, knn_dist, X1B, L1Wb, lse1_w, lse1_b, lse1_gw, lse1_gb,
        ST_GEO, nullptr, nullptr, nullptr, 0.f, P1Wb, pool1_b, ST_P1, Z1);
    // lse2 + pool2 (xprev = raw Z1, pool1 GN+relu folded into gather) -> Z2 + ST_P2
    lse_pool_kernel<256,16><<<Bc * Nc / 16, 256, 0, stream>>>(
        coords, knn_idx, knn_dist, Z1, L2Wb, lse2_w, lse2_b, lse2_gw, lse2_gb,
        ST_GEO, ST_P1, pool1_gw, pool1_gb, (float)(8 * Nc), P2Wb, pool2_b, ST_P2, Z2);
    // final: mlp2(GN+relu(Z2) folded into staging) + GN(S) -> leaky 0.01 -> f32
    gemm_conv<256,512,32,3><<<dim3(Nc/128, 4, Bc), 256, 0, stream>>>(
        M2Wb, Z2, mlp2_b, nullptr, out, nullptr, SB, ST_SC, sc_gw, sc_gb,
        (float)(32 * Nc), ST_P2, pool2_gw, pool2_gb, (float)(16 * Nc));
}

// Round 6
// 334.656 us; speedup vs baseline: 1.1057x; 1.1057x over previous
//
#include <hip/hip_runtime.h>

// LocalFeatureAggregation — bf16-MFMA pipeline, point-major activations.
// B=2, N=16384, K=16, D_IN=128, D_OUT=256, GROUPS=16.
//
// Round-6 changes (r5 pool-fusion REVERTED — it re-streamed 128KB of pool
// weights per 16-pt block):
//  - lse_param_kernel (1 block): closed-form geo-GN stats -> per (stage,b,o)
//    pscale/pshift. lse_m no longer recomputes them per block; epilogue is
//    one FMA+relu; lse_m has ONE barrier (was 3).
//  - lse_m Bbuf zero-pass folded into the geo writes (4 x b128 per column).
//  - sc conv + mlp1 merged into one GEMM dispatch (MODE 4, COUT 512+128).

constexpr int Bc = 2;
constexpr int Nc = 16384;
constexpr int Kc = 16;
constexpr float EPSc = 1e-6f;

typedef __attribute__((ext_vector_type(8))) short short8;
typedef __attribute__((ext_vector_type(4))) short short4v;
typedef __attribute__((ext_vector_type(4))) float floatx4;

__device__ inline short f2bf(float x) {
    union { float f; unsigned u; } v; v.f = x;
    unsigned r = v.u + 0x7fffu + ((v.u >> 16) & 1u);
    return (short)(r >> 16);
}
__device__ inline float bf2f(short s) {
    union { unsigned u; float f; } v;
    v.u = ((unsigned)(unsigned short)s) << 16;
    return v.f;
}

// ---- workspace layout ----
// f32 ST[2048]: ST_SC=0, ST_P1=64, ST_P2=128, ST_GEO=256 (B x 65),
//               ST_LP=512: [stage][b][{psc,psh}x128] = 2*512 floats (512..1535)
// then bf16 (short) region, offsets in shorts:
constexpr size_t OW_P1W = 0;                        // 128*256
constexpr size_t OW_P2W = OW_P1W + 128*256;         // 256*256
constexpr size_t OW_M2W = OW_P2W + 256*256;         // 512*256
constexpr size_t OW_SCW = OW_M2W + 512*256;         // 512*128 (sc rows 0..511)
constexpr size_t OW_W1  = OW_SCW + 512*128;         // 128*128 (rows 512..639)
constexpr size_t OW_L1W = OW_W1  + 128*128;         // 128*32 (K padded)
constexpr size_t OW_L2W = OW_L1W + 128*32;          // 128*32
constexpr size_t OW_FB  = OW_L2W + 128*32;          // B*N*128
constexpr size_t OW_X1  = OW_FB  + (size_t)Bc*Nc*128;
constexpr size_t OW_M   = OW_X1  + (size_t)Bc*Nc*128;
constexpr size_t OW_Z1  = OW_M   + (size_t)Bc*Nc*256;
constexpr size_t OW_Z2  = OW_Z1  + (size_t)Bc*Nc*128;
constexpr size_t OW_S   = OW_Z2  + (size_t)Bc*Nc*256;

// prep_kernel segment bounds (elements)
constexpr int CV0 = 128*256;            // pool1_w
constexpr int CV1 = CV0 + 256*256;      // pool2_w
constexpr int CV2 = CV1 + 512*256;      // mlp2_w
constexpr int CV3 = CV2 + 512*128;      // sc_w
constexpr int CV4 = CV3 + 128*128;      // w1
constexpr int CV5 = CV4 + 128*32;       // lse1_w padded
constexpr int CV6 = CV5 + 128*32;       // lse2_w padded
constexpr int CVTOT = CV6 + 512;        // + zero ST[0..511]

__global__ void prep_kernel(const float* __restrict__ p1w,
                            const float* __restrict__ p2w,
                            const float* __restrict__ m2w,
                            const float* __restrict__ scw,
                            const float* __restrict__ w1,
                            const float* __restrict__ l1w,
                            const float* __restrict__ l2w,
                            short* __restrict__ W16,
                            float* __restrict__ ST)
{
    int i = blockIdx.x * 256 + threadIdx.x;
    if (i < CV0) { W16[OW_P1W + i] = f2bf(p1w[i]); return; }
    if (i < CV1) { int k = i - CV0; W16[OW_P2W + k] = f2bf(p2w[k]); return; }
    if (i < CV2) { int k = i - CV1; W16[OW_M2W + k] = f2bf(m2w[k]); return; }
    if (i < CV3) { int k = i - CV2; W16[OW_SCW + k] = f2bf(scw[k]); return; }
    if (i < CV4) { int k = i - CV3; W16[OW_W1  + k] = f2bf(w1[k]); return; }
    if (i < CV5) { int k = i - CV4; int o = k >> 5, c = k & 31;
                   W16[OW_L1W + k] = (c < 10) ? f2bf(l1w[o*10+c]) : (short)0; return; }
    if (i < CV6) { int k = i - CV5; int o = k >> 5, c = k & 31;
                   W16[OW_L2W + k] = (c < 10) ? f2bf(l2w[o*10+c]) : (short)0; return; }
    { int k = i - CV6; if (k < 512) ST[k] = 0.f; }
}

// features f32 [b][128][N] -> FB bf16 [b][N][128]
__global__ void feat_t_kernel(const float* __restrict__ in, short* __restrict__ out) {
    int tid  = threadIdx.x;
    int lane = tid & 63, wave = tid >> 6;
    int bb = blockIdx.x / (Nc / 64);
    int n  = (blockIdx.x % (Nc / 64)) * 64 + lane;
    #pragma unroll
    for (int cc = 0; cc < 4; cc++) {
        int c0 = (wave + cc * 4) * 8;
        short8 sv;
        #pragma unroll
        for (int i = 0; i < 8; i++)
            sv[i] = f2bf(in[((size_t)bb * 128 + c0 + i) * Nc + n]);
        *(short8*)&out[((size_t)(bb * Nc + n)) * 128 + c0] = sv;
    }
}

// Reduce S (10) and Q upper-tri (55) of geo over all (n,k), per batch.
__launch_bounds__(256)
__global__ void geo_reduce_kernel(const float* __restrict__ coords,
                                  const int* __restrict__ knn_idx,
                                  const float* __restrict__ knn_dist,
                                  float* __restrict__ dst)   // [B][65]
{
    __shared__ float part[4][65];
    const int tid  = threadIdx.x;
    const int b    = blockIdx.y;
    const int base = blockIdx.x * 256 + tid;          // gridDim.x = 256
    const float* cb  = coords   + (size_t)b * Nc * 3;
    const int*   ib  = knn_idx  + (size_t)b * Nc * Kc;
    const float* db  = knn_dist + (size_t)b * Nc * Kc;

    float acc[65];
    #pragma unroll
    for (int i = 0; i < 65; i++) acc[i] = 0.f;

    #pragma unroll
    for (int it = 0; it < 4; it++) {
        int r = base + it * 65536;                    // covers Nc*Kc = 262144
        int n = r >> 4;
        float cx = cb[n*3+0], cy = cb[n*3+1], cz = cb[n*3+2];
        int   j  = ib[r];
        float nx = cb[j*3+0], ny = cb[j*3+1], nz = cb[j*3+2];
        float d  = db[r];
        float g[10] = {cx,cy,cz,nx,ny,nz,cx-nx,cy-ny,cz-nz,d};
        #pragma unroll
        for (int c = 0; c < 10; c++) acc[c] += g[c];
        int idx = 10;
        #pragma unroll
        for (int c = 0; c < 10; c++)
            #pragma unroll
            for (int c2 = c; c2 < 10; c2++) acc[idx++] += g[c] * g[c2];
    }
    #pragma unroll
    for (int i = 0; i < 65; i++) {
        float v = acc[i];
        #pragma unroll
        for (int off = 1; off < 64; off <<= 1) v += __shfl_xor(v, off);
        acc[i] = v;
    }
    int lane = tid & 63, wave = tid >> 6;
    if (lane == 0) {
        #pragma unroll
        for (int i = 0; i < 65; i++) part[wave][i] = acc[i];
    }
    __syncthreads();
    if (tid < 65) {
        float s = part[0][tid] + part[1][tid] + part[2][tid] + part[3][tid];
        atomicAdd(&dst[b * 65 + tid], s);
    }
}

// Closed-form geo-GN params: for (stage s, batch b, channel o):
//   sum_y = NK*bias + w.S ; sum_y2 = NK*b^2 + 2b(w.S) + w^T Q w
//   group (8ch) mean/var -> pscale = iv*gw, pshift = (bias-mu)*pscale + gb.
// One block, 512 threads = (s,b,o).
__launch_bounds__(512)
__global__ void lse_param_kernel(const float* __restrict__ geoS,  // [B][65]
                                 const float* __restrict__ l1w,
                                 const float* __restrict__ l1b,
                                 const float* __restrict__ l1gw,
                                 const float* __restrict__ l1gb,
                                 const float* __restrict__ l2w,
                                 const float* __restrict__ l2b,
                                 const float* __restrict__ l2gw,
                                 const float* __restrict__ l2gb,
                                 float* __restrict__ lp)          // ST+512
{
    __shared__ float osum[512], osq[512];
    const int tid = threadIdx.x;
    const int s = tid >> 8, r = tid & 255, b = r >> 7, o = r & 127;
    const float* wf = s ? l2w : l1w;
    const float* bf = s ? l2b : l1b;
    const float* gwf = s ? l2gw : l1gw;
    const float* gbf = s ? l2gb : l1gb;
    const float NK = (float)(Nc * Kc);
    const float* S = geoS + b * 65;

    float w[10];
    #pragma unroll
    for (int c = 0; c < 10; c++) w[c] = wf[o * 10 + c];
    float wS = 0.f;
    #pragma unroll
    for (int c = 0; c < 10; c++) wS += w[c] * S[c];
    float q = 0.f;
    {
        int idx = 10;
        #pragma unroll
        for (int c = 0; c < 10; c++)
            #pragma unroll
            for (int c2 = c; c2 < 10; c2++) {
                float t = w[c] * w[c2] * S[idx++];
                q += (c == c2) ? t : 2.f * t;
            }
    }
    float bo = bf[o];
    osum[tid] = NK * bo + wS;
    osq[tid]  = NK * bo * bo + 2.f * bo * wS + q;
    __syncthreads();
    int gb0 = tid & ~7;
    float gs = 0.f, gq = 0.f;
    #pragma unroll
    for (int i = 0; i < 8; i++) { gs += osum[gb0 + i]; gq += osq[gb0 + i]; }
    float cnt  = 8.f * NK;
    float mean = gs / cnt;
    float var  = gq / cnt - mean * mean;
    float iv   = rsqrtf(var + EPSc);
    float psc  = iv * gwf[o];
    float psh  = (bo - mean) * psc + gbf[o];
    lp[s * 512 + b * 256 + o]       = psc;
    lp[s * 512 + b * 256 + 128 + o] = psh;
}

// GEMM: out[b][n][o] = sum_c W[o][c] * X[b][n][c] + bias[o]   (point-major)
// MODE 1: leaky 0.2 -> bf16.  MODE 2: raw bf16 + group stats atomics.
// MODE 3: final — B normalized in staging (pool2 GN+relu), epilogue
//         v + GN(sbuf) -> leaky 0.01 -> f32 [b][o][n].
// MODE 4: merged sc(512, raw+stats)/mlp1(128, leaky0.2) by mo tile.
template<int CIN, int COUT, int GROUP_CH, int MODE>
__launch_bounds__(256)
__global__ void gemm_conv(const short* __restrict__ wA,   // [COUT][CIN] bf16
                          const short* __restrict__ xB,   // [b][N][CIN] bf16
                          const float* __restrict__ bias,
                          short* __restrict__ outb,
                          float* __restrict__ outf,
                          float* __restrict__ stats,
                          const short* __restrict__ sbuf, // [b][N][512] bf16
                          const float* __restrict__ st_sc,
                          const float* __restrict__ gw,
                          const float* __restrict__ gb,
                          float sc_cnt,
                          const float* __restrict__ bst,  // MODE 3: pool2 stats
                          const float* __restrict__ bgw,
                          const float* __restrict__ bgb,
                          float bcnt,
                          const float* __restrict__ bias2, // MODE 4: mlp1 bias
                          short* __restrict__ outb2)       // MODE 4: X1 out
{
    __shared__ short Abuf[128 * 40];
    __shared__ short Bbuf[128 * 40];
    __shared__ float sstat[32];
    __shared__ float smean[4], sinv[4];
    __shared__ float bsc[256], bsh[256];

    const int tid  = threadIdx.x;
    const int n0   = blockIdx.x * 128;
    const int mo   = blockIdx.y * 128;
    const int b    = blockIdx.z;
    const int lane = tid & 63;
    const int wave = tid >> 6;
    const int wm   = (wave >> 1) * 64;
    const int wn   = (wave & 1) * 64;
    const int l15  = lane & 15;
    const int quad = lane >> 4;
    const bool sc_tile = (MODE == 4) && (mo < 512);

    if constexpr (MODE == 2 || MODE == 4) { if (tid < 32) sstat[tid] = 0.f; }
    if constexpr (MODE == 3) {
        if (tid < 4) {
            int g = (mo >> 5) + tid;
            float s0 = st_sc[(b * 16 + g) * 2 + 0];
            float s1 = st_sc[(b * 16 + g) * 2 + 1];
            float mean = s0 / sc_cnt;
            float var  = s1 / sc_cnt - mean * mean;
            smean[tid] = mean;
            sinv[tid]  = rsqrtf(var + EPSc);
        }
        if (tid < CIN) {   // pool2 GN: 256 ch, 16 ch/group
            int g = tid >> 4;
            float s0 = bst[(b * 16 + g) * 2 + 0];
            float s1 = bst[(b * 16 + g) * 2 + 1];
            float mean = s0 / bcnt;
            float var  = s1 / bcnt - mean * mean;
            float inv  = rsqrtf(var + EPSc);
            float sc_  = inv * bgw[tid];
            bsc[tid] = sc_;
            bsh[tid] = bgb[tid] - mean * sc_;
        }
    }

    floatx4 acc[4][4];
    #pragma unroll
    for (int mi = 0; mi < 4; mi++)
        #pragma unroll
        for (int ni = 0; ni < 4; ni++)
            acc[mi][ni] = (floatx4){0.f, 0.f, 0.f, 0.f};

    const short* wAr = wA + (size_t)mo * CIN;
    const short* xBr = xB + (size_t)b * Nc * CIN + (size_t)n0 * CIN;

    for (int c0 = 0; c0 < CIN; c0 += 32) {
        __syncthreads();
        #pragma unroll
        for (int s = 0; s < 2; s++) {
            int e = tid + s * 256;
            int r = e >> 2, q = e & 3;
            *(short8*)&Abuf[r * 40 + q * 8] =
                *(const short8*)(wAr + (size_t)r * CIN + c0 + q * 8);
            short8 v = *(const short8*)(xBr + (size_t)r * CIN + c0 + q * 8);
            if constexpr (MODE == 3) {
                #pragma unroll
                for (int i = 0; i < 8; i++) {
                    int ch = c0 + q * 8 + i;
                    float t = bf2f(v[i]) * bsc[ch] + bsh[ch];
                    v[i] = f2bf(t > 0.f ? t : 0.f);
                }
            }
            *(short8*)&Bbuf[r * 40 + q * 8] = v;
        }
        __syncthreads();

        short8 af[4], bfr[4];
        #pragma unroll
        for (int mi = 0; mi < 4; mi++)
            af[mi] = *(short8*)&Abuf[(wm + mi * 16 + l15) * 40 + quad * 8];
        #pragma unroll
        for (int ni = 0; ni < 4; ni++)
            bfr[ni] = *(short8*)&Bbuf[(wn + ni * 16 + l15) * 40 + quad * 8];
        #pragma unroll
        for (int mi = 0; mi < 4; mi++)
            #pragma unroll
            for (int ni = 0; ni < 4; ni++)
                acc[mi][ni] = __builtin_amdgcn_mfma_f32_16x16x32_bf16(
                    af[mi], bfr[ni], acc[mi][ni], 0, 0, 0);
    }

    // D row(o) = mo+wm+mi*16+quad*4+r, col(n) = n0+wn+ni*16+l15
    #pragma unroll
    for (int mi = 0; mi < 4; mi++) {
        int rowl = wm + mi * 16 + quad * 4;
        float b4[4], gw4[4], gb4[4];
        #pragma unroll
        for (int r = 0; r < 4; r++) {
            if constexpr (MODE == 4) {
                b4[r] = sc_tile ? bias[mo + rowl + r] : bias2[mo - 512 + rowl + r];
            } else {
                b4[r] = bias[mo + rowl + r];
            }
            if constexpr (MODE == 3) {
                gw4[r] = gw[mo + rowl + r];
                gb4[r] = gb[mo + rowl + r];
            }
        }
        float gs = 0.f, gq = 0.f;
        #pragma unroll
        for (int ni = 0; ni < 4; ni++) {
            int col = n0 + wn + ni * 16 + l15;
            if constexpr (MODE == 3) {
                short4v s4 = *(const short4v*)&sbuf[((size_t)(b * Nc + col)) * 512 + mo + rowl];
                int gl = rowl >> 5;
                #pragma unroll
                for (int r = 0; r < 4; r++) {
                    float v = acc[mi][ni][r] + b4[r];
                    float s = bf2f(s4[r]);
                    float sn = (s - smean[gl]) * sinv[gl] * gw4[r] + gb4[r];
                    float o = v + sn;
                    o = o > 0.f ? o : 0.01f * o;
                    outf[((size_t)b * COUT + mo + rowl + r) * Nc + col] = o;
                }
            } else if constexpr (MODE == 4) {
                short4v sv;
                #pragma unroll
                for (int r = 0; r < 4; r++) {
                    float v = acc[mi][ni][r] + b4[r];
                    if (sc_tile) { gs += v; gq += v * v; }
                    else v = v > 0.f ? v : 0.2f * v;
                    sv[r] = f2bf(v);
                }
                if (sc_tile)
                    *(short4v*)&outb[((size_t)(b * Nc + col)) * 512 + mo + rowl] = sv;
                else
                    *(short4v*)&outb2[((size_t)(b * Nc + col)) * 128 + mo - 512 + rowl] = sv;
            } else {
                short4v sv;
                #pragma unroll
                for (int r = 0; r < 4; r++) {
                    float v = acc[mi][ni][r] + b4[r];
                    if constexpr (MODE == 1) v = v > 0.f ? v : 0.2f * v;
                    if constexpr (MODE == 2) { gs += v; gq += v * v; }
                    sv[r] = f2bf(v);
                }
                *(short4v*)&outb[((size_t)(b * Nc + col)) * COUT + mo + rowl] = sv;
            }
        }
        if ((MODE == 2) || (MODE == 4 && sc_tile)) {
            #pragma unroll
            for (int off = 1; off < 16; off <<= 1) {
                gs += __shfl_xor(gs, off);
                gq += __shfl_xor(gq, off);
            }
            if (l15 == 0) {
                int gl = rowl / GROUP_CH;
                atomicAdd(&sstat[gl * 2 + 0], gs);
                atomicAdd(&sstat[gl * 2 + 1], gq);
            }
        }
    }
    if ((MODE == 2) || (MODE == 4 && sc_tile)) {
        __syncthreads();
        constexpr int NG = 128 / GROUP_CH;
        if (tid < 2 * NG) {
            int g0 = mo / GROUP_CH;
            atomicAdd(&stats[b * 32 + (g0 + (tid >> 1)) * 2 + (tid & 1)], sstat[tid]);
        }
    }
}

// LSE: per 16-point tile, ONE barrier.
//  - geo conv via MFMA (A-frags from global, GN via precomputed pscale/pshift)
//    + relu + mean_k -> m[n][0:128]
//  - neighbor gather-mean of point-major xprev -> m[n][128:256]
//    (optional folded pool1-GN+relu on xprev)
__launch_bounds__(256)
__global__ void lse_m_kernel(const float* __restrict__ coords,
                             const int* __restrict__ knn_idx,
                             const float* __restrict__ knn_dist,
                             const short* __restrict__ xprev,   // [b][N][128] bf16
                             const short* __restrict__ wpad,    // [128][32] bf16
                             const float* __restrict__ lp,      // [b][{psc,psh}x128]
                             const float* __restrict__ xst,     // pool1 stats or null
                             const float* __restrict__ xgw,
                             const float* __restrict__ xgb,
                             float xcnt,
                             short* __restrict__ m)             // [b][N][256] bf16
{
    __shared__ short Bbuf[256 * 40];
    __shared__ int   jl[256];
    __shared__ float xscs[128], xshs[128];

    const int tid = threadIdx.x;
    const int b   = blockIdx.x >> 10;          // Nc/16 = 1024
    const int n0  = (blockIdx.x & 1023) * 16;
    const bool norm = (xst != nullptr);

    if (norm && tid < 128) {   // pool1 GN fold: 128 ch, 8 ch/group
        int g = tid >> 3;
        float s0 = xst[(b * 16 + g) * 2 + 0];
        float s1 = xst[(b * 16 + g) * 2 + 1];
        float mean = s0 / xcnt;
        float var  = s1 / xcnt - mean * mean;
        float inv  = rsqrtf(var + EPSc);
        float sc_  = inv * xgw[tid];
        xscs[tid] = sc_;
        xshs[tid] = xgb[tid] - mean * sc_;
    }
    // geo features for the 16x16 (pt,k) tile -> Bbuf[col=k*16+pt][c], rows
    // 10..31 zeroed inline (K padded to 32).
    {
        int pt = tid & 15, k = tid >> 4;
        int n  = n0 + pt;
        const float* cb = coords + (size_t)b * Nc * 3;
        float cx = cb[n*3+0], cy = cb[n*3+1], cz = cb[n*3+2];
        int   j  = knn_idx[((size_t)b * Nc + n) * Kc + k];
        float nx = cb[j*3+0], ny = cb[j*3+1], nz = cb[j*3+2];
        float d  = knn_dist[((size_t)b * Nc + n) * Kc + k];
        int col = k * 16 + pt;
        short8 w0, w1, zz;
        w0[0]=f2bf(cx); w0[1]=f2bf(cy); w0[2]=f2bf(cz);
        w0[3]=f2bf(nx); w0[4]=f2bf(ny); w0[5]=f2bf(nz);
        w0[6]=f2bf(cx-nx); w0[7]=f2bf(cy-ny);
        w1[0]=f2bf(cz-nz); w1[1]=f2bf(d);
        #pragma unroll
        for (int i = 2; i < 8; i++) w1[i] = 0;
        #pragma unroll
        for (int i = 0; i < 8; i++) zz[i] = 0;
        *(short8*)&Bbuf[col * 40 + 0]  = w0;
        *(short8*)&Bbuf[col * 40 + 8]  = w1;
        *(short8*)&Bbuf[col * 40 + 16] = zz;
        *(short8*)&Bbuf[col * 40 + 24] = zz;
        jl[col] = j;
    }
    __syncthreads();

    const int lane = tid & 63, wave = tid >> 6;
    const int l15 = lane & 15, quad = lane >> 4;
    // B fragments: tile ni <-> neighbor k, lane col <-> pt
    short8 bfr[16];
    #pragma unroll
    for (int ni = 0; ni < 16; ni++)
        bfr[ni] = *(short8*)&Bbuf[(ni * 16 + l15) * 40 + quad * 8];
    #pragma unroll
    for (int mt2 = 0; mt2 < 2; mt2++) {
        int mt = wave * 2 + mt2;
        short8 af = *(const short8*)(wpad + (mt * 16 + l15) * 32 + quad * 8);
        floatx4 acc[16];
        #pragma unroll
        for (int ni = 0; ni < 16; ni++) {
            acc[ni] = (floatx4){0.f, 0.f, 0.f, 0.f};
            acc[ni] = __builtin_amdgcn_mfma_f32_16x16x32_bf16(af, bfr[ni], acc[ni], 0, 0, 0);
        }
        short4v sv;
        #pragma unroll
        for (int r = 0; r < 4; r++) {
            int o = mt * 16 + quad * 4 + r;
            float psc = lp[b * 256 + o];
            float psh = lp[b * 256 + 128 + o];
            float s = 0.f;
            #pragma unroll
            for (int ni = 0; ni < 16; ni++) {
                float v = acc[ni][r] * psc + psh;
                s += v > 0.f ? v : 0.f;
            }
            sv[r] = f2bf(s * (1.f / 16.f));
        }
        *(short4v*)&m[((size_t)(b * Nc + n0 + l15)) * 256 + mt * 16 + quad * 4] = sv;
    }

    // neighbor gather-mean: thread (cs, tp), 16 x b128 loads
    {
        int tp = tid & 15, cs = tid >> 4;
        float sc8[8], sh8[8];
        if (norm) {
            #pragma unroll
            for (int i = 0; i < 8; i++) { sc8[i] = xscs[cs*8+i]; sh8[i] = xshs[cs*8+i]; }
        }
        float acc8[8];
        #pragma unroll
        for (int i = 0; i < 8; i++) acc8[i] = 0.f;
        #pragma unroll
        for (int k = 0; k < 16; k++) {
            int j = jl[k * 16 + tp];
            short8 v = *(const short8*)&xprev[((size_t)(b * Nc + j)) * 128 + cs * 8];
            if (norm) {
                #pragma unroll
                for (int i = 0; i < 8; i++) {
                    float t = bf2f(v[i]) * sc8[i] + sh8[i];
                    acc8[i] += t > 0.f ? t : 0.f;
                }
            } else {
                #pragma unroll
                for (int i = 0; i < 8; i++) acc8[i] += bf2f(v[i]);
            }
        }
        short8 sv;
        #pragma unroll
        for (int i = 0; i < 8; i++) sv[i] = f2bf(acc8[i] * (1.f / 16.f));
        *(short8*)&m[((size_t)(b * Nc + n0 + tp)) * 256 + 128 + cs * 8] = sv;
    }
}

extern "C" void kernel_launch(void* const* d_in, const int* in_sizes, int n_in,
                              void* d_out, int out_size, void* d_ws, size_t ws_size,
                              hipStream_t stream)
{
    const float* coords   = (const float*)d_in[0];
    const float* features = (const float*)d_in[1];
    const float* knn_dist = (const float*)d_in[2];
    const int*   knn_idx  = (const int*)  d_in[3];
    const float* w1       = (const float*)d_in[4];
    const float* b1       = (const float*)d_in[5];
    const float* lse1_w   = (const float*)d_in[6];
    const float* lse1_b   = (const float*)d_in[7];
    const float* lse1_gw  = (const float*)d_in[8];
    const float* lse1_gb  = (const float*)d_in[9];
    const float* pool1_w  = (const float*)d_in[10];
    const float* pool1_b  = (const float*)d_in[11];
    const float* pool1_gw = (const float*)d_in[12];
    const float* pool1_gb = (const float*)d_in[13];
    const float* lse2_w   = (const float*)d_in[14];
    const float* lse2_b   = (const float*)d_in[15];
    const float* lse2_gw  = (const float*)d_in[16];
    const float* lse2_gb  = (const float*)d_in[17];
    const float* pool2_w  = (const float*)d_in[18];
    const float* pool2_b  = (const float*)d_in[19];
    const float* pool2_gw = (const float*)d_in[20];
    const float* pool2_gb = (const float*)d_in[21];
    const float* mlp2_w   = (const float*)d_in[22];
    const float* mlp2_b   = (const float*)d_in[23];
    const float* sc_w     = (const float*)d_in[24];
    const float* sc_b     = (const float*)d_in[25];
    const float* sc_gw    = (const float*)d_in[26];
    const float* sc_gb    = (const float*)d_in[27];
    (void)in_sizes; (void)n_in; (void)out_size; (void)ws_size;

    float* ST = (float*)d_ws;           // 2048 floats
    float* ST_SC  = ST + 0;
    float* ST_P1  = ST + 64;
    float* ST_P2  = ST + 128;
    float* ST_GEO = ST + 256;           // B x 65
    float* ST_LP  = ST + 512;           // [stage][b][{psc,psh}x128]
    short* W16 = (short*)(ST + 2048);
    short* P1Wb = W16 + OW_P1W;
    short* P2Wb = W16 + OW_P2W;
    short* M2Wb = W16 + OW_M2W;
    short* SCWb = W16 + OW_SCW;         // rows 0..511 sc, 512..639 w1
    short* L1Wb = W16 + OW_L1W;
    short* L2Wb = W16 + OW_L2W;
    short* FB   = W16 + OW_FB;
    short* X1B  = W16 + OW_X1;
    short* MB   = W16 + OW_M;
    short* Z1   = W16 + OW_Z1;
    short* Z2   = W16 + OW_Z2;
    short* SB   = W16 + OW_S;
    float* out  = (float*)d_out;

    prep_kernel<<<(CVTOT + 255) / 256, 256, 0, stream>>>(
        pool1_w, pool2_w, mlp2_w, sc_w, w1, lse1_w, lse2_w, W16, ST);
    feat_t_kernel<<<Bc * Nc / 64, 256, 0, stream>>>(features, FB);
    geo_reduce_kernel<<<dim3(256, Bc), 256, 0, stream>>>(
        coords, knn_idx, knn_dist, ST_GEO);
    lse_param_kernel<<<1, 512, 0, stream>>>(
        ST_GEO, lse1_w, lse1_b, lse1_gw, lse1_gb,
        lse2_w, lse2_b, lse2_gw, lse2_gb, ST_LP);

    // merged sc (512, raw bf16 + stats, group=32ch) + mlp1 (128, leaky 0.2)
    gemm_conv<128,640,32,4><<<dim3(Nc/128, 5, Bc), 256, 0, stream>>>(
        SCWb, FB, sc_b, SB, nullptr, ST_SC, nullptr, nullptr, nullptr, nullptr, 0.f,
        nullptr, nullptr, nullptr, 0.f, b1, X1B);
    // lse1 (xprev = X1B, no fold) -> MB
    lse_m_kernel<<<Bc * Nc / 16, 256, 0, stream>>>(
        coords, knn_idx, knn_dist, X1B, L1Wb, ST_LP,
        nullptr, nullptr, nullptr, 0.f, MB);
    // pool1: 256 -> 128 + stats (group=8ch), raw Z1
    gemm_conv<256,128,8,2><<<dim3(Nc/128, 1, Bc), 256, 0, stream>>>(
        P1Wb, MB, pool1_b, Z1, nullptr, ST_P1, nullptr, nullptr, nullptr, nullptr, 0.f,
        nullptr, nullptr, nullptr, 0.f, nullptr, nullptr);
    // lse2 (xprev = raw Z1, pool1 GN+relu folded into gather) -> MB
    lse_m_kernel<<<Bc * Nc / 16, 256, 0, stream>>>(
        coords, knn_idx, knn_dist, Z1, L2Wb, ST_LP + 512,
        ST_P1, pool1_gw, pool1_gb, (float)(8 * Nc), MB);
    // pool2: 256 -> 256 + stats (group=16ch), raw Z2
    gemm_conv<256,256,16,2><<<dim3(Nc/128, 2, Bc), 256, 0, stream>>>(
        P2Wb, MB, pool2_b, Z2, nullptr, ST_P2, nullptr, nullptr, nullptr, nullptr, 0.f,
        nullptr, nullptr, nullptr, 0.f, nullptr, nullptr);
    // final: mlp2(GN+relu(Z2) folded into staging) + GN(S) -> leaky 0.01 -> f32
    gemm_conv<256,512,32,3><<<dim3(Nc/128, 4, Bc), 256, 0, stream>>>(
        M2Wb, Z2, mlp2_b, nullptr, out, nullptr, SB, ST_SC, sc_gw, sc_gb,
        (float)(32 * Nc), ST_P2, pool2_gw, pool2_gb, (float)(16 * Nc),
        nullptr, nullptr);
}